// Round 2
// baseline (135.950 us; speedup 1.0000x reference)
//
#include <hip/hip_runtime.h>
#include <hip/hip_bf16.h>

#define NN 50000      // nodes
#define EE 800000     // edges
#define KD 512        // IN_DIM
#define ND 256        // H*D

typedef __bf16 bf16x8 __attribute__((ext_vector_type(8)));
typedef float f32x4 __attribute__((ext_vector_type(4)));

// ---------- Kernel 1: fused  (a) W (512x256 f32) -> Wt (256x512 bf16 [n][k])
//                             (b) zero the flags array ----------
__global__ __launch_bounds__(256) void prep_kernel(const float* __restrict__ W,
                                                   __hip_bfloat16* __restrict__ Wt,
                                                   unsigned char* __restrict__ flags) {
    if (blockIdx.x >= 32) {
        int idx = (blockIdx.x - 32) * 256 + threadIdx.x;
        if (idx < 3125) reinterpret_cast<uint4*>(flags)[idx] = (uint4){0, 0, 0, 0};
        return;
    }
    __shared__ __align__(16) __hip_bfloat16 tile[64][72];
    const int bk = blockIdx.x & 7;
    const int bn = blockIdx.x >> 3;
    const int k0 = bk * 64, n0 = bn * 64;
    const int t = threadIdx.x;
    const int r = t >> 2;
    const int c = (t & 3) * 16;
    const float4* src = reinterpret_cast<const float4*>(W + (size_t)(k0 + r) * ND + n0 + c);
#pragma unroll
    for (int i = 0; i < 4; ++i) {
        float4 f = src[i];
        tile[c + i * 4 + 0][r] = __float2bfloat16(f.x);
        tile[c + i * 4 + 1][r] = __float2bfloat16(f.y);
        tile[c + i * 4 + 2][r] = __float2bfloat16(f.z);
        tile[c + i * 4 + 3][r] = __float2bfloat16(f.w);
    }
    __syncthreads();
    uint4* dst = reinterpret_cast<uint4*>(Wt + (size_t)(n0 + r) * KD + k0 + c);
    dst[0] = *reinterpret_cast<const uint4*>(&tile[r][c]);
    dst[1] = *reinterpret_cast<const uint4*>(&tile[r][c + 8]);
}

// ---------- Kernel 2: flags[dst[e]] = 1 via test-and-set ----------
__global__ __launch_bounds__(256) void flag_set_kernel(const int* __restrict__ dst_idx,
                                                       unsigned char* __restrict__ flags) {
    int i = (blockIdx.x * 256 + threadIdx.x) * 4;
    if (i >= EE) return;  // EE % 4 == 0
    int4 d = *reinterpret_cast<const int4*>(dst_idx + i);
    if (flags[d.x] == 0) flags[d.x] = 1;
    if (flags[d.y] == 0) flags[d.y] = 1;
    if (flags[d.z] == 0) flags[d.z] = 1;
    if (flags[d.w] == 0) flags[d.w] = 1;
}

__device__ __forceinline__ bf16x8 cvt8(f32x4 lo, f32x4 hi) {
    union { __hip_bfloat16 h[8]; bf16x8 v; } u;
    u.h[0] = __float2bfloat16(lo[0]); u.h[1] = __float2bfloat16(lo[1]);
    u.h[2] = __float2bfloat16(lo[2]); u.h[3] = __float2bfloat16(lo[3]);
    u.h[4] = __float2bfloat16(hi[0]); u.h[5] = __float2bfloat16(hi[1]);
    u.h[6] = __float2bfloat16(hi[2]); u.h[7] = __float2bfloat16(hi[3]);
    return u.v;
}

// ---------- Kernel 3: out[m][n] = flags[m] ? (x @ W)[m][n] : 0 ----------
// LDS-free, barrier-free streaming GEMM. BM=64, BN=256 (full N -> x read 1x).
// 512 threads = 8 waves (2M x 4N), wave tile 32x64, acc[2][4].
// A fragments: per-lane f32x4 pairs straight from x (f32->bf16 at consume).
// B fragments: bf16x8 straight from Wt (256 KB, L2-resident -> always hits).
// Ping-pong register pipeline (P/Q, depth-2): per-step offsets are
// compile-time constants (kt*128 <= 1936 B for A, kt*64 <= 960 B for B) that
// fold into the global_load 13-bit imm -> ~zero address VALU in the loop.
// Fragment gather is 100% cacheline-efficient: each quarter-wave reads 16
// rows, the paired 16B loads fully consume each 64B line.
// Latency hiding via TLP: no barriers, ~124 VGPR -> 2 blocks/CU = 16 waves.
__global__ __launch_bounds__(512, 4) void gemm_mask_kernel(const float* __restrict__ x,
                                                           const __hip_bfloat16* __restrict__ Wt,
                                                           const unsigned char* __restrict__ flags,
                                                           float* __restrict__ out) {
    const int t = threadIdx.x;
    const int w = t >> 6;             // wave 0..7
    const int l = t & 63;
    const int wm = w >> 2;            // 0..1  (M half)
    const int wn = w & 3;             // 0..3  (N quarter)
    const int m_base = blockIdx.x * 64;

    const int fr = l & 15;            // fragment row within 16
    const int fo = l >> 4;            // k sub-block 0..3 (8 elems each)

    // ---- per-lane base pointers ----
    const char* aPtr[2];
    {
        int m0 = m_base + wm * 32 + fr;
        int m1 = m0 + 16;
        if (m0 > NN - 1) m0 = NN - 1;   // clamp (stores are guarded)
        if (m1 > NN - 1) m1 = NN - 1;
        aPtr[0] = (const char*)x + (size_t)m0 * (KD * 4) + fo * 32;
        aPtr[1] = (const char*)x + (size_t)m1 * (KD * 4) + fo * 32;
    }
    const char* bPtr[4];
#pragma unroll
    for (int tn = 0; tn < 4; ++tn)
        bPtr[tn] = (const char*)Wt + (size_t)(wn * 64 + tn * 16 + fr) * (KD * 2) + fo * 16;

    f32x4 acc[2][4];
#pragma unroll
    for (int i = 0; i < 2; ++i)
#pragma unroll
        for (int j = 0; j < 4; ++j) acc[i][j] = (f32x4){0.f, 0.f, 0.f, 0.f};

#define LOADSET(aS, bS, kt)                                                        \
    {                                                                              \
        _Pragma("unroll")                                                          \
        for (int tm = 0; tm < 2; ++tm) {                                           \
            aS[tm][0] = *reinterpret_cast<const f32x4*>(aPtr[tm] + (kt) * 128);    \
            aS[tm][1] = *reinterpret_cast<const f32x4*>(aPtr[tm] + (kt) * 128 + 16); \
        }                                                                          \
        _Pragma("unroll")                                                          \
        for (int tn = 0; tn < 4; ++tn)                                             \
            bS[tn] = *reinterpret_cast<const bf16x8*>(bPtr[tn] + (kt) * 64);       \
    }

#define COMPUTE(aS, bS)                                                            \
    {                                                                              \
        bf16x8 afr0 = cvt8(aS[0][0], aS[0][1]);                                    \
        bf16x8 afr1 = cvt8(aS[1][0], aS[1][1]);                                    \
        _Pragma("unroll")                                                          \
        for (int tn = 0; tn < 4; ++tn) {                                           \
            acc[0][tn] = __builtin_amdgcn_mfma_f32_16x16x32_bf16(afr0, bS[tn], acc[0][tn], 0, 0, 0); \
            acc[1][tn] = __builtin_amdgcn_mfma_f32_16x16x32_bf16(afr1, bS[tn], acc[1][tn], 0, 0, 0); \
        }                                                                          \
    }

    f32x4 aP[2][2], aQ[2][2];
    bf16x8 bP[4], bQ[4];
    LOADSET(aP, bP, 0);
    LOADSET(aQ, bQ, 1);
#pragma unroll
    for (int kt = 0; kt < 16; kt += 2) {
        COMPUTE(aP, bP);
        if (kt + 2 < 16) LOADSET(aP, bP, kt + 2);
        COMPUTE(aQ, bQ);
        if (kt + 3 < 16) LOADSET(aQ, bQ, kt + 3);
    }
#undef LOADSET
#undef COMPUTE

    // ---- epilogue: C/D layout col=lane&15, row=(lane>>4)*4+r ----
    const int col = l & 15;
    const int rq = (l >> 4) * 4;
#pragma unroll
    for (int tm = 0; tm < 2; ++tm) {
#pragma unroll
        for (int r = 0; r < 4; ++r) {
            const int m = m_base + wm * 32 + tm * 16 + rq + r;
            if (m < NN) {
                const float fl = (float)flags[m];
                float* orow = out + (size_t)m * ND + wn * 64 + col;
#pragma unroll
                for (int tn = 0; tn < 4; ++tn)
                    orow[tn * 16] = acc[tm][tn][r] * fl;
            }
        }
    }
}

extern "C" void kernel_launch(void* const* d_in, const int* in_sizes, int n_in,
                              void* d_out, int out_size, void* d_ws, size_t ws_size,
                              hipStream_t stream) {
    const float* x = (const float*)d_in[0];          // (N, 512) f32
    const int* edge_index = (const int*)d_in[1];     // (2, E) i32: row0=src, row1=dst
    const float* W = (const float*)d_in[3];          // (512, 256) f32
    float* out = (float*)d_out;                      // (N, 256) f32

    unsigned char* flags = (unsigned char*)d_ws;                       // NN bytes (16B-aligned)
    __hip_bfloat16* Wt = (__hip_bfloat16*)((char*)d_ws + 65536);       // 256 KB

    prep_kernel<<<45, 256, 0, stream>>>(W, Wt, flags);
    flag_set_kernel<<<(EE / 4 + 255) / 256, 256, 0, stream>>>(edge_index + EE, flags);
    gemm_mask_kernel<<<(NN + 63) / 64, 512, 0, stream>>>(x, Wt, flags, out);
}

// Round 3
// 54.282 us; speedup vs baseline: 2.5045x; 2.5045x over previous
//
#include <hip/hip_runtime.h>
#include <hip/hip_bf16.h>

#define NN 50000      // nodes
#define EE 800000     // edges
#define KD 512        // IN_DIM
#define ND 256        // H*D

typedef __bf16 bf16x8 __attribute__((ext_vector_type(8)));
typedef float f32x4 __attribute__((ext_vector_type(4)));

// fire-and-forget 16B global->LDS copy (dest = wave-uniform base + lane*16)
#define GLD16(g, l) __builtin_amdgcn_global_load_lds( \
    (const __attribute__((address_space(1))) unsigned int*)(g), \
    (__attribute__((address_space(3))) unsigned int*)(l), 16, 0, 0)

// ---------- Kernel 1: fused  (a) W (512x256 f32) -> Wt (256x512 bf16 [n][k])
//                             (b) zero the flags array ----------
__global__ __launch_bounds__(256) void prep_kernel(const float* __restrict__ W,
                                                   __hip_bfloat16* __restrict__ Wt,
                                                   unsigned char* __restrict__ flags) {
    if (blockIdx.x >= 32) {
        int idx = (blockIdx.x - 32) * 256 + threadIdx.x;
        if (idx < 3125) reinterpret_cast<uint4*>(flags)[idx] = (uint4){0, 0, 0, 0};
        return;
    }
    __shared__ __align__(16) __hip_bfloat16 tile[64][72];
    const int bk = blockIdx.x & 7;
    const int bn = blockIdx.x >> 3;
    const int k0 = bk * 64, n0 = bn * 64;
    const int t = threadIdx.x;
    const int r = t >> 2;
    const int c = (t & 3) * 16;
    const float4* src = reinterpret_cast<const float4*>(W + (size_t)(k0 + r) * ND + n0 + c);
#pragma unroll
    for (int i = 0; i < 4; ++i) {
        float4 f = src[i];
        tile[c + i * 4 + 0][r] = __float2bfloat16(f.x);
        tile[c + i * 4 + 1][r] = __float2bfloat16(f.y);
        tile[c + i * 4 + 2][r] = __float2bfloat16(f.z);
        tile[c + i * 4 + 3][r] = __float2bfloat16(f.w);
    }
    __syncthreads();
    uint4* dst = reinterpret_cast<uint4*>(Wt + (size_t)(n0 + r) * KD + k0 + c);
    dst[0] = *reinterpret_cast<const uint4*>(&tile[r][c]);
    dst[1] = *reinterpret_cast<const uint4*>(&tile[r][c + 8]);
}

// ---------- Kernel 2: flags[dst[e]] = 1 via test-and-set ----------
__global__ __launch_bounds__(256) void flag_set_kernel(const int* __restrict__ dst_idx,
                                                       unsigned char* __restrict__ flags) {
    int i = (blockIdx.x * 256 + threadIdx.x) * 4;
    if (i >= EE) return;  // EE % 4 == 0
    int4 d = *reinterpret_cast<const int4*>(dst_idx + i);
    if (flags[d.x] == 0) flags[d.x] = 1;
    if (flags[d.y] == 0) flags[d.y] = 1;
    if (flags[d.z] == 0) flags[d.z] = 1;
    if (flags[d.w] == 0) flags[d.w] = 1;
}

__device__ __forceinline__ bf16x8 cvt8(f32x4 lo, f32x4 hi) {
    union { __hip_bfloat16 h[8]; bf16x8 v; } u;
    u.h[0] = __float2bfloat16(lo[0]); u.h[1] = __float2bfloat16(lo[1]);
    u.h[2] = __float2bfloat16(lo[2]); u.h[3] = __float2bfloat16(lo[3]);
    u.h[4] = __float2bfloat16(hi[0]); u.h[5] = __float2bfloat16(hi[1]);
    u.h[6] = __float2bfloat16(hi[2]); u.h[7] = __float2bfloat16(hi[3]);
    return u.v;
}

// ---------- Kernel 3: out[m][n] = flags[m] ? (x @ W)[m][n] : 0 ----------
// BM=64, BN=256 (full N -> x read ONCE), BK=32.
// 512 threads = 8 waves (2M x 4N), wave tile 32x64, acc[2][4].
// All staging via global_load_lds (the only pipeline primitive that survives
// regalloc -- R2's register ping-pong collapsed to serial loads, VGPR=44).
// TRIPLE-buffered LDS (72 KB -> 2 blocks/CU = 16 waves/CU), prefetch depth 2:
// steady-state s_waitcnt vmcnt(6) keeps 2 k-steps (48 KB/block) in flight
// across barriers.
// LDS layouts (linear dest required by global_load_lds; swizzle applied to the
// per-lane GLOBAL source + the ds_read address -- both-sides, rule 21):
//   A buf 8 KB:  row m (0..63) x 128 B (32 f32 of k);  phys = log ^ ((m&7)<<4)
//   B buf 16 KB: row j (0..127) x 128 B = n=2j (64 B k-chunk) | n=2j+1 (64 B),
//                phys = log ^ ((j&7)<<4)
// Every 16-lane fragment ds_read then hits all 8 16B-slots exactly 2x
// -> 2-way = free (m136).
__global__ __launch_bounds__(512, 4) void gemm_mask_kernel(const float* __restrict__ x,
                                                           const __hip_bfloat16* __restrict__ Wt,
                                                           const unsigned char* __restrict__ flags,
                                                           float* __restrict__ out) {
    __shared__ __align__(16) char As[3][8192];
    __shared__ __align__(16) char Bs[3][16384];

    const int t = threadIdx.x;
    const int w = t >> 6;             // wave 0..7
    const int l = t & 63;
    const int wm = w >> 2;            // 0..1  (M half)
    const int wn = w & 3;             // 0..3  (N quarter)
    const int m_base = blockIdx.x * 64;

    // ---- staging sources (per-lane, inverse-swizzled) ----
    // A: dest byte o = w*1024 + l*16 ; row ar = o>>7 ; granule p=(o>>4)&7
    //    logical granule g = p ^ (ar&7) ; src = x[m_base+ar] + g*16 (+kt*128)
    const char* aSrc;
    {
        int o = w * 1024 + l * 16;
        int ar = o >> 7;
        int g = ((o >> 4) & 7) ^ (ar & 7);
        int m = m_base + ar; if (m > NN - 1) m = NN - 1;   // clamp (stores guarded)
        aSrc = (const char*)x + (size_t)m * (KD * 4) + g * 16;
    }
    // B: dest byte o = j*8192 + w*1024 + l*16 ; row j=o>>7 ; g = p ^ (j&7)
    //    n = 2j + (g>>2) ; src = Wt[n] + (g&3)*16 (+kt*64)
    const char* bSrc[2];
#pragma unroll
    for (int j = 0; j < 2; ++j) {
        int o = j * 8192 + w * 1024 + l * 16;
        int br = o >> 7;
        int g = ((o >> 4) & 7) ^ (br & 7);
        int n = 2 * br + (g >> 2);
        bSrc[j] = (const char*)Wt + (size_t)n * (KD * 2) + (g & 3) * 16;
    }

    // ---- consume-side ds_read offsets (swizzled) ----
    const int fr = l & 15;            // fragment row within 16
    const int fo = l >> 4;            // k sub-block 0..3
    // A: row = wm*32 + tm*16 + fr ; logical col = fo*32 (+16) ; row&7 == l&7
    const int aOff0 = (wm * 32 + fr) * 128 + ((fo * 32) ^ ((l & 7) << 4));
    const int aOff1 = aOff0 ^ 16;
    // B: n = wn*64 + tn*16 + fr ; j = n>>1 ; half = fr&1 ; j&7 = (fr>>1)&7
    const int bOff = (wn * 32 + (fr >> 1)) * 128 +
                     (((fr & 1) * 64 + fo * 16) ^ (((fr >> 1) & 7) << 4));

    f32x4 acc[2][4];
#pragma unroll
    for (int i = 0; i < 2; ++i)
#pragma unroll
        for (int j = 0; j < 4; ++j) acc[i][j] = (f32x4){0.f, 0.f, 0.f, 0.f};

#define STAGE(kt, buf)                                           \
    {                                                            \
        GLD16(aSrc + (kt) * 128, &As[buf][w * 1024]);            \
        GLD16(bSrc[0] + (kt) * 64, &Bs[buf][w * 1024]);          \
        GLD16(bSrc[1] + (kt) * 64, &Bs[buf][8192 + w * 1024]);   \
    }

    // prologue: 2 steps in flight (6 loads/wave)
    STAGE(0, 0);
    STAGE(1, 1);

#pragma unroll
    for (int kt = 0; kt < 16; ++kt) {
        const int cur = kt % 3;
        if (kt < 14) {
            STAGE(kt + 2, (kt + 2) % 3);   // buffer last read at step kt-1 (barrier-protected)
            asm volatile("s_waitcnt vmcnt(6)" ::: "memory");   // step kt landed; 6 stay in flight
        } else if (kt == 14) {
            asm volatile("s_waitcnt vmcnt(3)" ::: "memory");
        } else {
            asm volatile("s_waitcnt vmcnt(0)" ::: "memory");
        }
        __builtin_amdgcn_s_barrier();      // all waves' step-kt data in LDS
        __builtin_amdgcn_sched_barrier(0); // keep ds_reads below the barrier

        bf16x8 afr[2], bfr[4];
#pragma unroll
        for (int tm = 0; tm < 2; ++tm) {
            f32x4 lo = *reinterpret_cast<const f32x4*>(&As[cur][aOff0 + tm * 2048]);
            f32x4 hi = *reinterpret_cast<const f32x4*>(&As[cur][aOff1 + tm * 2048]);
            afr[tm] = cvt8(lo, hi);
        }
#pragma unroll
        for (int tn = 0; tn < 4; ++tn)
            bfr[tn] = *reinterpret_cast<const bf16x8*>(&Bs[cur][bOff + tn * 1024]);
#pragma unroll
        for (int tm = 0; tm < 2; ++tm)
#pragma unroll
            for (int tn = 0; tn < 4; ++tn)
                acc[tm][tn] = __builtin_amdgcn_mfma_f32_16x16x32_bf16(afr[tm], bfr[tn], acc[tm][tn], 0, 0, 0);

        __builtin_amdgcn_s_barrier();      // all waves done reading buf[cur]
    }
#undef STAGE

    // ---- epilogue: C/D layout col=lane&15, row=(lane>>4)*4+r ----
    const int col = l & 15;
    const int rq = (l >> 4) * 4;
#pragma unroll
    for (int tm = 0; tm < 2; ++tm) {
#pragma unroll
        for (int r = 0; r < 4; ++r) {
            const int m = m_base + wm * 32 + tm * 16 + rq + r;
            if (m < NN) {
                const float fl = (float)flags[m];
                float* orow = out + (size_t)m * ND + wn * 64 + col;
#pragma unroll
                for (int tn = 0; tn < 4; ++tn)
                    orow[tn * 16] = acc[tm][tn][r] * fl;
            }
        }
    }
}

extern "C" void kernel_launch(void* const* d_in, const int* in_sizes, int n_in,
                              void* d_out, int out_size, void* d_ws, size_t ws_size,
                              hipStream_t stream) {
    const float* x = (const float*)d_in[0];          // (N, 512) f32
    const int* edge_index = (const int*)d_in[1];     // (2, E) i32: row0=src, row1=dst
    const float* W = (const float*)d_in[3];          // (512, 256) f32
    float* out = (float*)d_out;                      // (N, 256) f32

    unsigned char* flags = (unsigned char*)d_ws;                       // NN bytes (16B-aligned)
    __hip_bfloat16* Wt = (__hip_bfloat16*)((char*)d_ws + 65536);       // 256 KB

    prep_kernel<<<45, 256, 0, stream>>>(W, Wt, flags);
    flag_set_kernel<<<(EE / 4 + 255) / 256, 256, 0, stream>>>(edge_index + EE, flags);
    gemm_mask_kernel<<<(NN + 63) / 64, 512, 0, stream>>>(x, Wt, flags, out);
}

// Round 4
// 53.758 us; speedup vs baseline: 2.5289x; 1.0098x over previous
//
#include <hip/hip_runtime.h>
#include <hip/hip_bf16.h>

#define NN 50000      // nodes
#define EE 800000     // edges
#define KD 512        // IN_DIM
#define ND 256        // H*D

typedef __bf16 bf16x8 __attribute__((ext_vector_type(8)));
typedef float f32x4 __attribute__((ext_vector_type(4)));

// fire-and-forget 16B global->LDS copy (dest = wave-uniform base + lane*16)
#define GLD16(g, l) __builtin_amdgcn_global_load_lds( \
    (const __attribute__((address_space(1))) unsigned int*)(g), \
    (__attribute__((address_space(3))) unsigned int*)(l), 16, 0, 0)

// ---------- Kernel 1: fused  (a) W (512x256 f32) -> Wt (256x512 bf16 [n][k])
//                             (b) zero the flags array ----------
__global__ __launch_bounds__(256) void prep_kernel(const float* __restrict__ W,
                                                   __hip_bfloat16* __restrict__ Wt,
                                                   unsigned char* __restrict__ flags) {
    if (blockIdx.x >= 32) {
        int idx = (blockIdx.x - 32) * 256 + threadIdx.x;
        if (idx < 3125) reinterpret_cast<uint4*>(flags)[idx] = (uint4){0, 0, 0, 0};
        return;
    }
    __shared__ __align__(16) __hip_bfloat16 tile[64][72];
    const int bk = blockIdx.x & 7;
    const int bn = blockIdx.x >> 3;
    const int k0 = bk * 64, n0 = bn * 64;
    const int t = threadIdx.x;
    const int r = t >> 2;
    const int c = (t & 3) * 16;
    const float4* src = reinterpret_cast<const float4*>(W + (size_t)(k0 + r) * ND + n0 + c);
#pragma unroll
    for (int i = 0; i < 4; ++i) {
        float4 f = src[i];
        tile[c + i * 4 + 0][r] = __float2bfloat16(f.x);
        tile[c + i * 4 + 1][r] = __float2bfloat16(f.y);
        tile[c + i * 4 + 2][r] = __float2bfloat16(f.z);
        tile[c + i * 4 + 3][r] = __float2bfloat16(f.w);
    }
    __syncthreads();
    uint4* dst = reinterpret_cast<uint4*>(Wt + (size_t)(n0 + r) * KD + k0 + c);
    dst[0] = *reinterpret_cast<const uint4*>(&tile[r][c]);
    dst[1] = *reinterpret_cast<const uint4*>(&tile[r][c + 8]);
}

// ---------- Kernel 2: flags[dst[e]] = 1 via test-and-set ----------
__global__ __launch_bounds__(256) void flag_set_kernel(const int* __restrict__ dst_idx,
                                                       unsigned char* __restrict__ flags) {
    int i = (blockIdx.x * 256 + threadIdx.x) * 4;
    if (i >= EE) return;  // EE % 4 == 0
    int4 d = *reinterpret_cast<const int4*>(dst_idx + i);
    if (flags[d.x] == 0) flags[d.x] = 1;
    if (flags[d.y] == 0) flags[d.y] = 1;
    if (flags[d.z] == 0) flags[d.z] = 1;
    if (flags[d.w] == 0) flags[d.w] = 1;
}

__device__ __forceinline__ bf16x8 cvt8(f32x4 lo, f32x4 hi) {
    union { __hip_bfloat16 h[8]; bf16x8 v; } u;
    u.h[0] = __float2bfloat16(lo[0]); u.h[1] = __float2bfloat16(lo[1]);
    u.h[2] = __float2bfloat16(lo[2]); u.h[3] = __float2bfloat16(lo[3]);
    u.h[4] = __float2bfloat16(hi[0]); u.h[5] = __float2bfloat16(hi[1]);
    u.h[6] = __float2bfloat16(hi[2]); u.h[7] = __float2bfloat16(hi[3]);
    return u.v;
}

// ---------- Kernel 3: out[m][n] = flags[m] ? (x @ W)[m][n] : 0 ----------
// BM=64, BN=256 (x read ONCE), BK=32. 512 threads = 8 waves (2M x 4N),
// wave tile 32x64, acc[2][4].
// R4 change vs R3: trade pipeline depth for CONCURRENCY. Evidence R0-R3:
// delivered stream stuck at 2.3-2.6 TB/s regardless of depth (R1 depth-1 ==
// R3 depth-2); m13's 6.3 TB/s copy runs ~32 waves/CU decoupled. So: DOUBLE
// buffer (48 KB LDS) -> 3 blocks/CU = 24 waves/CU, three independent block
// streams per CU; depth-1 counted vmcnt(3) (R1's proven-safe discipline:
// stage target buffer is protected by the previous end-of-iter barrier).
// __launch_bounds__(512,6) caps VGPR at 84 so registers don't limit the
// 24 waves (R3 used 52).
// Staging/swizzle math identical to R3 (verified):
//   A buf 8 KB:  row m (0..63) x 128 B (32 f32 of k);  phys = log ^ ((m&7)<<4)
//   B buf 16 KB: row j (0..127) x 128 B = n=2j | n=2j+1, phys = log ^ ((j&7)<<4)
// -> every 16-lane fragment ds_read is 2-way (free, m136).
__global__ __launch_bounds__(512, 6) void gemm_mask_kernel(const float* __restrict__ x,
                                                           const __hip_bfloat16* __restrict__ Wt,
                                                           const unsigned char* __restrict__ flags,
                                                           float* __restrict__ out) {
    __shared__ __align__(16) char As[2][8192];
    __shared__ __align__(16) char Bs[2][16384];

    const int t = threadIdx.x;
    const int w = t >> 6;             // wave 0..7
    const int l = t & 63;
    const int wm = w >> 2;            // 0..1  (M half)
    const int wn = w & 3;             // 0..3  (N quarter)
    const int m_base = blockIdx.x * 64;

    // ---- staging sources (per-lane, inverse-swizzled) ----
    // A: dest byte o = w*1024 + l*16 ; row ar = o>>7 ; granule p=(o>>4)&7
    //    logical granule g = p ^ (ar&7) ; src = x[m_base+ar] + g*16 (+kt*128)
    const char* aSrc;
    {
        int o = w * 1024 + l * 16;
        int ar = o >> 7;
        int g = ((o >> 4) & 7) ^ (ar & 7);
        int m = m_base + ar; if (m > NN - 1) m = NN - 1;   // clamp (stores guarded)
        aSrc = (const char*)x + (size_t)m * (KD * 4) + g * 16;
    }
    // B: dest byte o = j*8192 + w*1024 + l*16 ; row br=o>>7 ; g = p ^ (br&7)
    //    n = 2*br + (g>>2) ; src = Wt[n] + (g&3)*16 (+kt*64)
    const char* bSrc[2];
#pragma unroll
    for (int j = 0; j < 2; ++j) {
        int o = j * 8192 + w * 1024 + l * 16;
        int br = o >> 7;
        int g = ((o >> 4) & 7) ^ (br & 7);
        int n = 2 * br + (g >> 2);
        bSrc[j] = (const char*)Wt + (size_t)n * (KD * 2) + (g & 3) * 16;
    }

    // ---- consume-side ds_read offsets (swizzled) ----
    const int fr = l & 15;            // fragment row within 16
    const int fo = l >> 4;            // k sub-block 0..3
    // A: row = wm*32 + tm*16 + fr ; logical col = fo*32 (+16) ; row&7 == fr&7
    const int aOff0 = (wm * 32 + fr) * 128 + ((fo * 32) ^ ((l & 7) << 4));
    const int aOff1 = aOff0 ^ 16;
    // B: n = wn*64 + tn*16 + fr ; j = n>>1 ; half = fr&1 ; j&7 = (fr>>1)&7
    const int bOff = (wn * 32 + (fr >> 1)) * 128 +
                     (((fr & 1) * 64 + fo * 16) ^ (((fr >> 1) & 7) << 4));

    f32x4 acc[2][4];
#pragma unroll
    for (int i = 0; i < 2; ++i)
#pragma unroll
        for (int j = 0; j < 4; ++j) acc[i][j] = (f32x4){0.f, 0.f, 0.f, 0.f};

#define STAGE(kt, buf)                                           \
    {                                                            \
        GLD16(aSrc + (kt) * 128, &As[buf][w * 1024]);            \
        GLD16(bSrc[0] + (kt) * 64, &Bs[buf][w * 1024]);          \
        GLD16(bSrc[1] + (kt) * 64, &Bs[buf][8192 + w * 1024]);   \
    }

    // prologue: step 0 in flight (3 loads/wave)
    STAGE(0, 0);

#pragma unroll
    for (int kt = 0; kt < 16; ++kt) {
        const int cur = kt & 1;
        if (kt < 15) {
            STAGE(kt + 1, cur ^ 1);    // target buf last read at kt-1 (end-barrier-protected)
            asm volatile("s_waitcnt vmcnt(3)" ::: "memory");   // step kt landed; 3 stay in flight
        } else {
            asm volatile("s_waitcnt vmcnt(0)" ::: "memory");
        }
        __builtin_amdgcn_s_barrier();      // all waves' step-kt data in LDS
        __builtin_amdgcn_sched_barrier(0); // keep ds_reads below the barrier

        bf16x8 afr[2], bfr[4];
#pragma unroll
        for (int tm = 0; tm < 2; ++tm) {
            f32x4 lo = *reinterpret_cast<const f32x4*>(&As[cur][aOff0 + tm * 2048]);
            f32x4 hi = *reinterpret_cast<const f32x4*>(&As[cur][aOff1 + tm * 2048]);
            afr[tm] = cvt8(lo, hi);
        }
#pragma unroll
        for (int tn = 0; tn < 4; ++tn)
            bfr[tn] = *reinterpret_cast<const bf16x8*>(&Bs[cur][bOff + tn * 1024]);
#pragma unroll
        for (int tm = 0; tm < 2; ++tm)
#pragma unroll
            for (int tn = 0; tn < 4; ++tn)
                acc[tm][tn] = __builtin_amdgcn_mfma_f32_16x16x32_bf16(afr[tm], bfr[tn], acc[tm][tn], 0, 0, 0);

        __builtin_amdgcn_s_barrier();      // all waves done reading buf[cur]
    }
#undef STAGE

    // ---- epilogue: C/D layout col=lane&15, row=(lane>>4)*4+r ----
    const int col = l & 15;
    const int rq = (l >> 4) * 4;
#pragma unroll
    for (int tm = 0; tm < 2; ++tm) {
#pragma unroll
        for (int r = 0; r < 4; ++r) {
            const int m = m_base + wm * 32 + tm * 16 + rq + r;
            if (m < NN) {
                const float fl = (float)flags[m];
                float* orow = out + (size_t)m * ND + wn * 64 + col;
#pragma unroll
                for (int tn = 0; tn < 4; ++tn)
                    orow[tn * 16] = acc[tm][tn][r] * fl;
            }
        }
    }
}

extern "C" void kernel_launch(void* const* d_in, const int* in_sizes, int n_in,
                              void* d_out, int out_size, void* d_ws, size_t ws_size,
                              hipStream_t stream) {
    const float* x = (const float*)d_in[0];          // (N, 512) f32
    const int* edge_index = (const int*)d_in[1];     // (2, E) i32: row0=src, row1=dst
    const float* W = (const float*)d_in[3];          // (512, 256) f32
    float* out = (float*)d_out;                      // (N, 256) f32

    unsigned char* flags = (unsigned char*)d_ws;                       // NN bytes (16B-aligned)
    __hip_bfloat16* Wt = (__hip_bfloat16*)((char*)d_ws + 65536);       // 256 KB

    prep_kernel<<<45, 256, 0, stream>>>(W, Wt, flags);
    flag_set_kernel<<<(EE / 4 + 255) / 256, 256, 0, stream>>>(edge_index + EE, flags);
    gemm_mask_kernel<<<(NN + 63) / 64, 512, 0, stream>>>(x, Wt, flags, out);
}

// Round 5
// 44.630 us; speedup vs baseline: 3.0462x; 1.2045x over previous
//
#include <hip/hip_runtime.h>
#include <hip/hip_bf16.h>

#define NN 50000      // nodes
#define EE 800000     // edges
#define KD 512        // IN_DIM
#define ND 256        // H*D

typedef __bf16 bf16x8 __attribute__((ext_vector_type(8)));
typedef float f32x4 __attribute__((ext_vector_type(4)));

// fire-and-forget 16B global->LDS copy (dest = wave-uniform base + lane*16)
#define GLD16(g, l) __builtin_amdgcn_global_load_lds( \
    (const __attribute__((address_space(1))) unsigned int*)(g), \
    (__attribute__((address_space(3))) unsigned int*)(l), 16, 0, 0)

// ---------- Kernel 1: fused  (a) W (512x256 f32) -> Wt (256x512 bf16 [n][k])
//                             (b) zero the flags array ----------
__global__ __launch_bounds__(256) void prep_kernel(const float* __restrict__ W,
                                                   __hip_bfloat16* __restrict__ Wt,
                                                   unsigned char* __restrict__ flags) {
    if (blockIdx.x >= 32) {
        int idx = (blockIdx.x - 32) * 256 + threadIdx.x;
        if (idx < 3125) reinterpret_cast<uint4*>(flags)[idx] = (uint4){0, 0, 0, 0};
        return;
    }
    __shared__ __align__(16) __hip_bfloat16 tile[64][72];
    const int bk = blockIdx.x & 7;
    const int bn = blockIdx.x >> 3;
    const int k0 = bk * 64, n0 = bn * 64;
    const int t = threadIdx.x;
    const int r = t >> 2;
    const int c = (t & 3) * 16;
    const float4* src = reinterpret_cast<const float4*>(W + (size_t)(k0 + r) * ND + n0 + c);
#pragma unroll
    for (int i = 0; i < 4; ++i) {
        float4 f = src[i];
        tile[c + i * 4 + 0][r] = __float2bfloat16(f.x);
        tile[c + i * 4 + 1][r] = __float2bfloat16(f.y);
        tile[c + i * 4 + 2][r] = __float2bfloat16(f.z);
        tile[c + i * 4 + 3][r] = __float2bfloat16(f.w);
    }
    __syncthreads();
    uint4* dst = reinterpret_cast<uint4*>(Wt + (size_t)(n0 + r) * KD + k0 + c);
    dst[0] = *reinterpret_cast<const uint4*>(&tile[r][c]);
    dst[1] = *reinterpret_cast<const uint4*>(&tile[r][c + 8]);
}

// ---------- Kernel 2: flags[dst[e]] = 1 via test-and-set ----------
__global__ __launch_bounds__(256) void flag_set_kernel(const int* __restrict__ dst_idx,
                                                       unsigned char* __restrict__ flags) {
    int i = (blockIdx.x * 256 + threadIdx.x) * 4;
    if (i >= EE) return;  // EE % 4 == 0
    int4 d = *reinterpret_cast<const int4*>(dst_idx + i);
    if (flags[d.x] == 0) flags[d.x] = 1;
    if (flags[d.y] == 0) flags[d.y] = 1;
    if (flags[d.z] == 0) flags[d.z] = 1;
    if (flags[d.w] == 0) flags[d.w] = 1;
}

__device__ __forceinline__ bf16x8 cvt8(f32x4 lo, f32x4 hi) {
    union { __hip_bfloat16 h[8]; bf16x8 v; } u;
    u.h[0] = __float2bfloat16(lo[0]); u.h[1] = __float2bfloat16(lo[1]);
    u.h[2] = __float2bfloat16(lo[2]); u.h[3] = __float2bfloat16(lo[3]);
    u.h[4] = __float2bfloat16(hi[0]); u.h[5] = __float2bfloat16(hi[1]);
    u.h[6] = __float2bfloat16(hi[2]); u.h[7] = __float2bfloat16(hi[3]);
    return u.v;
}

// ---------- Kernel 3: out[m][n] = flags[m] ? (x @ W)[m][n] : 0 ----------
// R5: BM=128 (was 64), BN=256 (x read ONCE), BK=32.
// Rationale: R1-R4 showed delivered BW invariant to depth/concurrency; the
// unaddressed cost is TOTAL staged bytes -- BN=256 makes every block read all
// of Wt, so BM=64 staged 300 MB for a 105 MB problem. BM=128 cuts B re-reads
// 2x: 391 blocks x (A 256 KB + B 256 KB) = 200 MB. Wave tile 64x64 (acc[4][4])
// also doubles MFMA per barrier pair.
// 512 threads = 8 waves (2M x 4N). Double-buffered LDS 64 KB -> 2 blocks/CU.
// Depth-1 counted vmcnt(4) (4 GLD16/thread/step), R4's proven barrier
// discipline (stage target buffer protected by previous end-of-iter barrier).
// LDS layouts (linear dest for global_load_lds; swizzle on per-lane GLOBAL
// source + ds_read address -- both-sides, rule 21):
//   A buf 16 KB: row m (0..127) x 128 B (32 f32 of k); phys = log ^ ((m&7)<<4)
//   B buf 16 KB: row j (0..127) x 128 B = n=2j | n=2j+1; phys = log ^ ((j&7)<<4)
// Every 16-lane fragment ds_read is 2-way (free).
__global__ __launch_bounds__(512, 4) void gemm_mask_kernel(const float* __restrict__ x,
                                                           const __hip_bfloat16* __restrict__ Wt,
                                                           const unsigned char* __restrict__ flags,
                                                           float* __restrict__ out) {
    __shared__ __align__(16) char As[2][16384];
    __shared__ __align__(16) char Bs[2][16384];

    const int t = threadIdx.x;
    const int w = t >> 6;             // wave 0..7
    const int l = t & 63;
    const int wm = w >> 2;            // 0..1  (M half)
    const int wn = w & 3;             // 0..3  (N quarter)
    const int m_base = blockIdx.x * 128;

    // ---- staging sources (per-lane, inverse-swizzled) ----
    // A: dest byte o = i*8192 + w*1024 + l*16 ; row ar = o>>7 (0..127);
    //    granule p=(o>>4)&7 ; logical g = p ^ (ar&7);
    //    src = x[m_base+ar] + g*16 (+kt*128)
    const char* aSrc[2];
#pragma unroll
    for (int i = 0; i < 2; ++i) {
        int o = i * 8192 + w * 1024 + l * 16;
        int ar = o >> 7;
        int g = ((o >> 4) & 7) ^ (ar & 7);
        int m = m_base + ar; if (m > NN - 1) m = NN - 1;   // clamp (stores guarded)
        aSrc[i] = (const char*)x + (size_t)m * (KD * 4) + g * 16;
    }
    // B: dest byte o = i*8192 + w*1024 + l*16 ; row j=o>>7 ; g = p ^ (j&7)
    //    n = 2j + (g>>2) ; src = Wt[n] + (g&3)*16 (+kt*64)
    const char* bSrc[2];
#pragma unroll
    for (int i = 0; i < 2; ++i) {
        int o = i * 8192 + w * 1024 + l * 16;
        int br = o >> 7;
        int g = ((o >> 4) & 7) ^ (br & 7);
        int n = 2 * br + (g >> 2);
        bSrc[i] = (const char*)Wt + (size_t)n * (KD * 2) + (g & 3) * 16;
    }

    // ---- consume-side ds_read offsets (swizzled) ----
    const int fr = l & 15;            // fragment row within 16
    const int fo = l >> 4;            // k sub-block 0..3
    // A: row = wm*64 + tm*16 + fr ; row&7 == fr&7 == l&7 (tm*16, wm*64 = 0 mod 8)
    const int aOff0 = (wm * 64 + fr) * 128 + ((fo * 32) ^ ((l & 7) << 4));
    // B: n = wn*64 + tn*16 + fr ; j = n>>1 = wn*32 + tn*8 + (fr>>1); j&7=(fr>>1)&7
    const int bOff = (wn * 32 + (fr >> 1)) * 128 +
                     (((fr & 1) * 64 + fo * 16) ^ (((fr >> 1) & 7) << 4));

    f32x4 acc[4][4];
#pragma unroll
    for (int i = 0; i < 4; ++i)
#pragma unroll
        for (int j = 0; j < 4; ++j) acc[i][j] = (f32x4){0.f, 0.f, 0.f, 0.f};

#define STAGE(kt, buf)                                            \
    {                                                             \
        GLD16(aSrc[0] + (kt) * 128, &As[buf][w * 1024]);          \
        GLD16(aSrc[1] + (kt) * 128, &As[buf][8192 + w * 1024]);   \
        GLD16(bSrc[0] + (kt) * 64, &Bs[buf][w * 1024]);           \
        GLD16(bSrc[1] + (kt) * 64, &Bs[buf][8192 + w * 1024]);    \
    }

    // prologue: step 0 in flight (4 loads/wave)
    STAGE(0, 0);

#pragma unroll
    for (int kt = 0; kt < 16; ++kt) {
        const int cur = kt & 1;
        if (kt < 15) {
            STAGE(kt + 1, cur ^ 1);    // target buf last read at kt-1 (end-barrier-protected)
            asm volatile("s_waitcnt vmcnt(4)" ::: "memory");   // step kt landed; 4 stay in flight
        } else {
            asm volatile("s_waitcnt vmcnt(0)" ::: "memory");
        }
        __builtin_amdgcn_s_barrier();      // all waves' step-kt data in LDS
        __builtin_amdgcn_sched_barrier(0); // keep ds_reads below the barrier

        bf16x8 bfr[4];
#pragma unroll
        for (int tn = 0; tn < 4; ++tn)
            bfr[tn] = *reinterpret_cast<const bf16x8*>(&Bs[cur][bOff + tn * 1024]);
        // tm-halves keep live A fragments at 2 (register pressure: acc=64)
#pragma unroll
        for (int h = 0; h < 2; ++h) {
            bf16x8 afr[2];
#pragma unroll
            for (int u = 0; u < 2; ++u) {
                const int p = aOff0 + (h * 2 + u) * 2048;
                f32x4 lo = *reinterpret_cast<const f32x4*>(&As[cur][p]);
                f32x4 hi = *reinterpret_cast<const f32x4*>(&As[cur][p ^ 16]);
                afr[u] = cvt8(lo, hi);
            }
#pragma unroll
            for (int u = 0; u < 2; ++u)
#pragma unroll
                for (int tn = 0; tn < 4; ++tn)
                    acc[h * 2 + u][tn] = __builtin_amdgcn_mfma_f32_16x16x32_bf16(afr[u], bfr[tn], acc[h * 2 + u][tn], 0, 0, 0);
        }

        __builtin_amdgcn_s_barrier();      // all waves done reading buf[cur]
    }
#undef STAGE

    // ---- epilogue: C/D layout col=lane&15, row=(lane>>4)*4+r ----
    const int col = l & 15;
    const int rq = (l >> 4) * 4;
#pragma unroll
    for (int tm = 0; tm < 4; ++tm) {
#pragma unroll
        for (int r = 0; r < 4; ++r) {
            const int m = m_base + wm * 64 + tm * 16 + rq + r;
            if (m < NN) {
                const float fl = (float)flags[m];
                float* orow = out + (size_t)m * ND + wn * 64 + col;
#pragma unroll
                for (int tn = 0; tn < 4; ++tn)
                    orow[tn * 16] = acc[tm][tn][r] * fl;
            }
        }
    }
}

extern "C" void kernel_launch(void* const* d_in, const int* in_sizes, int n_in,
                              void* d_out, int out_size, void* d_ws, size_t ws_size,
                              hipStream_t stream) {
    const float* x = (const float*)d_in[0];          // (N, 512) f32
    const int* edge_index = (const int*)d_in[1];     // (2, E) i32: row0=src, row1=dst
    const float* W = (const float*)d_in[3];          // (512, 256) f32
    float* out = (float*)d_out;                      // (N, 256) f32

    unsigned char* flags = (unsigned char*)d_ws;                       // NN bytes (16B-aligned)
    __hip_bfloat16* Wt = (__hip_bfloat16*)((char*)d_ws + 65536);       // 256 KB

    prep_kernel<<<45, 256, 0, stream>>>(W, Wt, flags);
    flag_set_kernel<<<(EE / 4 + 255) / 256, 256, 0, stream>>>(edge_index + EE, flags);
    gemm_mask_kernel<<<(NN + 127) / 128, 512, 0, stream>>>(x, Wt, flags, out);
}